// Round 2
// baseline (2130.826 us; speedup 1.0000x reference)
//
#include <hip/hip_runtime.h>
#include <hip/hip_fp16.h>

// HGNN: 3 layers of e = act(A @ (A^T @ e)), N=150000, E=4.8M, D=64.
// Build: atomic-free counting scatter + per-bucket LDS counting sort.
// Edges packed to 4B: col(18b) | val as 14-bit fixed point (vals in [0,1),
// abs err <= 6.1e-5, << fp16 feature error). Pad word 0 decodes to w=0.
// SpMM (mid layers): K=4 feature-column split (16 dims = 32B rows, 4.8MB
// table per group) with groups PINNED to XCD pairs via grp=(blockIdx.x&7)>>1
// (block ids round-robin the 8 XCDs) -> each XCD's L2 holds exactly one
// table for the whole dispatch; gather over-fetch ~= compulsory.
// 2 lanes per row -> one coalesced 32B L2 request per edge-visit.
// Final layer: full-row k_spmm_f (LN + residual fused, fp32 out) on the
// grouped layout.

#define NTOT 150000
#define NE   4800000
#define DD   64
#define NB   147            // buckets of 1024 rows
#define NBLK 512            // build blocks
#define EPB  9375           // edges per build block
#define GRP_I4 (NTOT * 2)   // int4 units per 16-dim group table (32B rows)
#define GRID_V 4688         // 8 XCD-residues x 586 row-blocks (128 rows/blk)

typedef unsigned int nt_u2 __attribute__((ext_vector_type(2)));
typedef int          nt_i4 __attribute__((ext_vector_type(4)));

// ---------- phase 1: per-block bucket histogram (no global atomics) ----------
__global__ __launch_bounds__(256) void k_hist(const int* __restrict__ rows,
                                              const int* __restrict__ cols,
                                              int* __restrict__ histR,
                                              int* __restrict__ histC) {
    __shared__ int hR[NB], hC[NB];
    const int tid = threadIdx.x, blk = blockIdx.x;
    for (int i = tid; i < NB; i += 256) { hR[i] = 0; hC[i] = 0; }
    __syncthreads();
    const int e0 = blk * EPB;
    const int e1 = min(NE, e0 + EPB);
    for (int e = e0 + tid; e < e1; e += 256) {
        atomicAdd(&hR[rows[e] >> 10], 1);
        atomicAdd(&hC[cols[e] >> 10], 1);
    }
    __syncthreads();
    for (int i = tid; i < NB; i += 256) {
        histR[i * NBLK + blk] = hR[i];
        histC[i * NBLK + blk] = hC[i];
    }
}

// ---------- phase 2: exclusive scan of [bucket][block] + bucket bounds ----------
__global__ __launch_bounds__(1024) void k_scan2(int* __restrict__ hR, int* __restrict__ hC,
                                                int* __restrict__ bbR, int* __restrict__ bbC) {
    __shared__ int wtot[16], wexcl[16];
    __shared__ int ctot;
    int* a  = blockIdx.x ? hC  : hR;
    int* bb = blockIdx.x ? bbC : bbR;
    const int n = NB * NBLK;
    const int tid  = threadIdx.x;
    const int lane = tid & 63, wv = tid >> 6;
    int carry = 0;
    for (int base = 0; base < n; base += 1024) {
        const int i = base + tid;
        const int v = (i < n) ? a[i] : 0;
        int s = v;
        #pragma unroll
        for (int off = 1; off < 64; off <<= 1) {
            int t = __shfl_up(s, off);
            if (lane >= off) s += t;
        }
        if (lane == 63) wtot[wv] = s;
        __syncthreads();
        if (tid == 0) {
            int run = 0;
            #pragma unroll
            for (int w = 0; w < 16; ++w) { wexcl[w] = run; run += wtot[w]; }
            ctot = run;
        }
        __syncthreads();
        if (i < n) a[i] = carry + wexcl[wv] + (s - v);
        carry += ctot;
        __syncthreads();
    }
    for (int i = tid; i <= NB; i += 1024) bb[i] = (i < NB) ? a[i * NBLK] : NE;
}

// ---------- phase 3: bin edges; cursors in LDS (block-private ranges) ----------
__global__ __launch_bounds__(256) void k_bin(const int* __restrict__ rows,
                                             const int* __restrict__ cols,
                                             const float* __restrict__ vals,
                                             const int* __restrict__ histR,
                                             const int* __restrict__ histC,
                                             int2* __restrict__ binR,
                                             int2* __restrict__ binC) {
    __shared__ int cR[NB], cC[NB];
    const int tid = threadIdx.x, blk = blockIdx.x;
    for (int i = tid; i < NB; i += 256) {
        cR[i] = histR[i * NBLK + blk];
        cC[i] = histC[i * NBLK + blk];
    }
    __syncthreads();
    const int e0 = blk * EPB;
    const int e1 = min(NE, e0 + EPB);
    for (int e = e0 + tid; e < e1; e += 256) {
        const int r = rows[e], c = cols[e];
        const int vb = __float_as_int(vals[e]);
        int p = atomicAdd(&cR[r >> 10], 1);
        int2 pr; pr.x = ((r & 1023) << 18) | c; pr.y = vb;
        binR[p] = pr;
        int q = atomicAdd(&cC[c >> 10], 1);
        int2 pc; pc.x = ((c & 1023) << 18) | r; pc.y = vb;
        binC[q] = pc;
    }
}

// ---------- phase 4: per-bucket LDS counting sort -> packed 4B CSR/CSC ----------
__global__ __launch_bounds__(1024) void k_sort(const int* __restrict__ bbR,
                                               const int2* __restrict__ binR,
                                               unsigned int* __restrict__ csr, int* __restrict__ startsR,
                                               const int* __restrict__ bbC,
                                               const int2* __restrict__ binC,
                                               unsigned int* __restrict__ csc, int* __restrict__ startsC) {
    __shared__ int hist[1024];
    __shared__ int cur[1024];
    __shared__ int wtot[16], wexcl[16];
    const int tid = threadIdx.x;
    const int lane = tid & 63, wv = tid >> 6;
    const int dir = (blockIdx.x >= NB) ? 1 : 0;
    const int b = blockIdx.x - dir * NB;
    const int*  bb     = dir ? bbC     : bbR;
    const int2* bin    = dir ? binC    : binR;
    unsigned int* out  = dir ? csc     : csr;
    int*        starts = dir ? startsC : startsR;
    const int ebase = bb[b];
    const int eend  = bb[b + 1];
    hist[tid] = 0;
    __syncthreads();
    for (int i = ebase + tid; i < eend; i += 1024)
        atomicAdd(&hist[((unsigned)bin[i].x) >> 18], 1);
    __syncthreads();
    const int v = hist[tid];
    int s = v;
    #pragma unroll
    for (int off = 1; off < 64; off <<= 1) { int t = __shfl_up(s, off); if (lane >= off) s += t; }
    if (lane == 63) wtot[wv] = s;
    __syncthreads();
    if (tid == 0) { int run = 0; for (int w = 0; w < 16; ++w) { wexcl[w] = run; run += wtot[w]; } }
    __syncthreads();
    const int excl = ebase + wexcl[wv] + (s - v);
    const int r0 = b << 10;
    if (r0 + tid < NTOT) starts[r0 + tid] = excl;
    cur[tid] = excl;
    __syncthreads();
    for (int i = ebase + tid; i < eend; i += 1024) {
        const int2 ed = bin[i];
        const int lr = ((unsigned)ed.x) >> 18;
        const int pos = atomicAdd(&cur[lr], 1);
        int qv = (int)(__int_as_float(ed.y) * 16384.f);   // floor quantize, val in [0,1)
        qv = qv > 16383 ? 16383 : qv;
        out[pos] = ((unsigned)ed.x & 0x3FFFFu) | ((unsigned)qv << 18);
    }
    if (blockIdx.x == 0 && tid == 0) { startsR[NTOT] = NE; startsC[NTOT] = NE; }
}

// ---------- ego fp32 -> fp16 in 4-group layout (16 dims = 2 int4 per row) ----------
__global__ __launch_bounds__(256) void k_cvt_g(const float4* __restrict__ x,
                                               int4* __restrict__ y) {
    const int tid  = threadIdx.x;
    const int rloc = tid >> 3;
    const int g    = (tid >> 1) & 3;
    const int half = tid & 1;
    const int r    = blockIdx.x * 32 + rloc;
    if (r >= NTOT) return;
    const float4 f0 = x[r * 16 + g * 4 + half * 2];
    const float4 f1 = x[r * 16 + g * 4 + half * 2 + 1];
    int4 o;
    __half2* oh = (__half2*)&o;
    oh[0] = __floats2half2_rn(f0.x, f0.y);
    oh[1] = __floats2half2_rn(f0.z, f0.w);
    oh[2] = __floats2half2_rn(f1.x, f1.y);
    oh[3] = __floats2half2_rn(f1.z, f1.w);
    y[g * GRP_I4 + r * 2 + half] = o;
}

// ---------- K=4 split pull SpMM, XCD-pinned groups, 2 lanes/row ----------
// MODE 0: plain -> half; MODE 1: LeakyReLU(0.5) -> half
#define ONE_EDGE(II) { \
    const unsigned int u = __builtin_nontemporal_load(edges + (II)); \
    const int4 q = xt[(u & 0x3FFFFu) * 2]; \
    const float w = (float)(u >> 18) * 6.103515625e-05f; \
    const __half2* h = (const __half2*)&q; \
    _Pragma("unroll") \
    for (int k = 0; k < 4; ++k) { \
        const float2 f = __half22float2(h[k]); \
        acc[2 * k]     = fmaf(w, f.x, acc[2 * k]); \
        acc[2 * k + 1] = fmaf(w, f.y, acc[2 * k + 1]); \
    } }

template <int MODE>
__global__ __launch_bounds__(256) void k_spmm_v(const int* __restrict__ starts,
                                                const unsigned int* __restrict__ edges,
                                                const int4* __restrict__ xg,
                                                int4* __restrict__ yg) {
    const int m    = blockIdx.x & 7;    // XCD residue (blocks round-robin XCDs)
    const int grp  = m >> 1;            // one 4.8MB table per XCD pair -> L2-resident
    const int rblk = blockIdx.x >> 3;   // 0..585
    const int half = threadIdx.x & 1;   // int4 within 32B row
    const int rloc = threadIdx.x >> 1;  // 0..127
    const int row  = (rblk * 2 + (m & 1)) * 128 + rloc;
    if (row >= NTOT) return;
    const int4* __restrict__ xt = xg + grp * GRP_I4 + half;
    const int s = starts[row];
    const int e = starts[row + 1];
    float acc[8];
    #pragma unroll
    for (int k = 0; k < 8; ++k) acc[k] = 0.f;
    int i = s;
    if ((i & 1) && i < e) { ONE_EDGE(i); ++i; }
    for (; i + 2 <= e; i += 2) {
        const nt_u2 uu = __builtin_nontemporal_load((const nt_u2*)edges + (i >> 1));
        const unsigned int u0 = uu.x, u1 = uu.y;
        const int4 q0 = xt[(u0 & 0x3FFFFu) * 2];
        const int4 q1 = xt[(u1 & 0x3FFFFu) * 2];
        const float w0 = (float)(u0 >> 18) * 6.103515625e-05f;
        const float w1 = (float)(u1 >> 18) * 6.103515625e-05f;
        const __half2* h0 = (const __half2*)&q0;
        const __half2* h1 = (const __half2*)&q1;
        #pragma unroll
        for (int k = 0; k < 4; ++k) {
            const float2 f0 = __half22float2(h0[k]);
            acc[2 * k]     = fmaf(w0, f0.x, acc[2 * k]);
            acc[2 * k + 1] = fmaf(w0, f0.y, acc[2 * k + 1]);
        }
        #pragma unroll
        for (int k = 0; k < 4; ++k) {
            const float2 f1 = __half22float2(h1[k]);
            acc[2 * k]     = fmaf(w1, f1.x, acc[2 * k]);
            acc[2 * k + 1] = fmaf(w1, f1.y, acc[2 * k + 1]);
        }
    }
    if (i < e) { ONE_EDGE(i); }
    if (MODE == 1) {
        #pragma unroll
        for (int k = 0; k < 8; ++k) acc[k] = acc[k] > 0.f ? acc[k] : 0.5f * acc[k];
    }
    int4 o;
    __half2* oh = (__half2*)&o;
    #pragma unroll
    for (int k = 0; k < 4; ++k) oh[k] = __floats2half2_rn(acc[2 * k], acc[2 * k + 1]);
    __builtin_nontemporal_store(*(const nt_i4*)&o, (nt_i4*)(yg + grp * GRP_I4 + row * 2 + half));
}

// ---------- full-row pull SpMM + LayerNorm + residual (final layer) ----------
__global__ __launch_bounds__(256) void k_spmm_f(const int* __restrict__ starts,
                                                const unsigned int* __restrict__ edges,
                                                const int4* __restrict__ xh,   // grouped table base
                                                float* __restrict__ out,
                                                const float* __restrict__ gamma,
                                                const float* __restrict__ beta,
                                                const float* __restrict__ ego) {
    const int gid  = blockIdx.x * 256 + threadIdx.x;
    const int wid  = gid >> 6;
    const int lane = threadIdx.x & 63;
    if (wid >= NTOT) return;
    const int g = lane >> 3;       // edge group 0..7
    const int l = lane & 7;        // 16B chunk within 128B row (dims 8l..8l+7)
    const int hoff = (l >> 1) * GRP_I4 + (l & 1);
    const int s  = starts[wid];
    const int e2 = starts[wid + 1];
    float acc[8];
    #pragma unroll
    for (int k = 0; k < 8; ++k) acc[k] = 0.f;
    for (int base = s; base < e2; base += 64) {
        const int idx = base + lane;
        unsigned int ed = 0u;
        if (idx < e2) ed = __builtin_nontemporal_load(edges + idx);
        const int nb = min(e2 - base, 64);
        for (int j = 0; j < nb; j += 8) {
            const int sel = j + g;
            const unsigned int ue = (unsigned int)__shfl((int)ed, sel);
            const int   c = (int)(ue & 0x3FFFFu);
            const float v = (float)(ue >> 18) * 6.103515625e-05f;  // pad(0) -> v=0
            const int4 q = xh[c * 2 + hoff];
            const __half2* h2 = (const __half2*)&q;
            #pragma unroll
            for (int k = 0; k < 4; ++k) {
                const float2 f = __half22float2(h2[k]);
                acc[2 * k]     = fmaf(v, f.x, acc[2 * k]);
                acc[2 * k + 1] = fmaf(v, f.y, acc[2 * k + 1]);
            }
        }
    }
    #pragma unroll
    for (int off = 8; off < 64; off <<= 1) {
        #pragma unroll
        for (int k = 0; k < 8; ++k) acc[k] += __shfl_xor(acc[k], off);
    }
    // LayerNorm over 64 cols: acc replicated across the 8 groups; reduce over l.
    float s1 = 0.f;
    #pragma unroll
    for (int k = 0; k < 8; ++k) s1 += acc[k];
    #pragma unroll
    for (int off = 1; off < 8; off <<= 1) s1 += __shfl_xor(s1, off);
    const float mu = s1 * (1.f / 64.f);
    float d[8], q2 = 0.f;
    #pragma unroll
    for (int k = 0; k < 8; ++k) { d[k] = acc[k] - mu; q2 += d[k] * d[k]; }
    #pragma unroll
    for (int off = 1; off < 8; off <<= 1) q2 += __shfl_xor(q2, off);
    const float rs = rsqrtf(q2 * (1.f / 64.f) + 1e-5f);
    if (lane < 8) {
        const float4* g4 = (const float4*)gamma;
        const float4* b4 = (const float4*)beta;
        const float4* e4 = (const float4*)ego + (size_t)wid * 16;
        float4*       o4 = (float4*)out + (size_t)wid * 16;
        #pragma unroll
        for (int half = 0; half < 2; ++half) {
            const float4 gg = g4[2 * l + half];
            const float4 bb = b4[2 * l + half];
            const float4 ee = e4[2 * l + half];
            float4 o;
            o.x = d[4 * half + 0] * rs * gg.x + bb.x + ee.x;
            o.y = d[4 * half + 1] * rs * gg.y + bb.y + ee.y;
            o.z = d[4 * half + 2] * rs * gg.z + bb.z + ee.z;
            o.w = d[4 * half + 3] * rs * gg.w + bb.w + ee.w;
            o4[2 * l + half] = o;
        }
    }
}

// ---------- fallback: atomic push (only if ws too small) ----------
__global__ __launch_bounds__(256) void k_push(const int* __restrict__ src_idx,
                                              const int* __restrict__ dst_idx,
                                              const float* __restrict__ vals,
                                              const float* __restrict__ x,
                                              float* __restrict__ y) {
    int gid  = blockIdx.x * 256 + threadIdx.x;
    int e    = gid >> 6;
    int lane = gid & 63;
    if (e >= NE) return;
    atomicAdd(&y[dst_idx[e] * DD + lane], vals[e] * x[src_idx[e] * DD + lane]);
}

__global__ __launch_bounds__(256) void k_leaky(float* __restrict__ x, int n) {
    int i = blockIdx.x * 256 + threadIdx.x;
    if (i < n) { float v = x[i]; x[i] = v > 0.f ? v : 0.5f * v; }
}

__global__ __launch_bounds__(256) void k_ln(const float* __restrict__ z,
                                            const float* __restrict__ gamma,
                                            const float* __restrict__ beta,
                                            const float* __restrict__ ego,
                                            float* __restrict__ out) {
    int gid  = blockIdx.x * 256 + threadIdx.x;
    int wid  = gid >> 6;
    int lane = threadIdx.x & 63;
    if (wid >= NTOT) return;
    float v = z[wid * DD + lane];
    float sum = v;
    #pragma unroll
    for (int off = 32; off; off >>= 1) sum += __shfl_xor(sum, off);
    float mu = sum * (1.f / 64.f);
    float d  = v - mu;
    float vs = d * d;
    #pragma unroll
    for (int off = 32; off; off >>= 1) vs += __shfl_xor(vs, off);
    float rs = rsqrtf(vs * (1.f / 64.f) + 1e-5f);
    out[wid * DD + lane] = d * rs * gamma[lane] + beta[lane] + ego[wid * DD + lane];
}

extern "C" void kernel_launch(void* const* d_in, const int* in_sizes, int n_in,
                              void* d_out, int out_size, void* d_ws, size_t ws_size,
                              hipStream_t stream) {
    const float* ego   = (const float*)d_in[0];
    const float* vals  = (const float*)d_in[1];
    const float* gamma = (const float*)d_in[2];
    const float* beta  = (const float*)d_in[3];
    const int*   rows  = (const int*)d_in[4];
    const int*   cols  = (const int*)d_in[5];
    float* out = (float*)d_out;

    const size_t SEG   = (size_t)NE * 8;          // 38,400,000 (region stride)
    const size_t SMETA = 600064;
    const size_t NEED  = 3 * SEG + 2 * SMETA + 1280;

    if (ws_size >= NEED) {
        char* w = (char*)d_ws;
        unsigned int* csr = (unsigned int*)w;            // 19.2MB used of SEG
        unsigned int* csc = (unsigned int*)(w + SEG);
        int2* binR = (int2*)(w + 2 * SEG);
        int2* binC = (int2*)d_out;                 // d_out as scratch pre-output
        int* histR = (int*)w;                      // aliases csr region (dead until k_sort)
        int* histC = (int*)(w + SEG);
        int* startsR = (int*)(w + 3 * SEG);
        int* startsC = (int*)(w + 3 * SEG + SMETA);
        int* bbR     = (int*)(w + 3 * SEG + 2 * SMETA);
        int* bbC     = bbR + (NB + 1);
        // feature buffers (4 group tables, 19.2MB each) alias dead build scratch
        int4* B1 = (int4*)(w + 2 * SEG);
        int4* B2 = (int4*)(w + 2 * SEG + SEG / 2);
        int4* EG = (int4*)d_out;                   // egoh in d_out (dead binC region)

        k_hist <<<NBLK, 256, 0, stream>>>(rows, cols, histR, histC);
        k_scan2<<<2, 1024, 0, stream>>>(histR, histC, bbR, bbC);
        k_bin  <<<NBLK, 256, 0, stream>>>(rows, cols, vals, histR, histC, binR, binC);
        k_sort <<<2 * NB, 1024, 0, stream>>>(bbR, binR, csr, startsR, bbC, binC, csc, startsC);
        k_cvt_g<<<GRID_V, 256, 0, stream>>>((const float4*)ego, EG);

        k_spmm_v<0><<<GRID_V, 256, 0, stream>>>(startsC, csc, EG, B1);
        k_spmm_v<1><<<GRID_V, 256, 0, stream>>>(startsR, csr, B1, B2);
        k_spmm_v<0><<<GRID_V, 256, 0, stream>>>(startsC, csc, B2, B1);
        k_spmm_v<1><<<GRID_V, 256, 0, stream>>>(startsR, csr, B1, B2);
        k_spmm_v<0><<<GRID_V, 256, 0, stream>>>(startsC, csc, B2, B1);
        k_spmm_f<<<(NTOT * 64) / 256, 256, 0, stream>>>(startsR, csr, B1, out, gamma, beta, ego);
    } else {
        const size_t FEAT_BYTES = (size_t)NTOT * DD * 4;
        float* B1 = (float*)d_ws;
        float* B2 = out;
        const int GRID_P = NE / 4;
        const int GRID_N = (NTOT * DD) / 256;
        const float* e = ego;
        for (int layer = 0; layer < 3; ++layer) {
            hipMemsetAsync(B1, 0, FEAT_BYTES, stream);
            k_push<<<GRID_P, 256, 0, stream>>>(rows, cols, vals, e, B1);
            hipMemsetAsync(B2, 0, FEAT_BYTES, stream);
            k_push<<<GRID_P, 256, 0, stream>>>(cols, rows, vals, B1, B2);
            if (layer < 2) {
                k_leaky<<<GRID_N, 256, 0, stream>>>(B2, NTOT * DD);
                e = B2;
            } else {
                k_ln<<<GRID_N, 256, 0, stream>>>(B2, gamma, beta, ego, out);
            }
        }
    }
}